// Round 8
// baseline (156.797 us; speedup 1.0000x reference)
//
#include <hip/hip_runtime.h>
#include <cstdint>

#define TPB 256
#define PRE_PB 128       // prefix columns taken from EACH batch (2*PRE_PB = 256)
#define ROWS_PB 64       // K1: rows per block (quad-split: 4 threads per row)
#define RNG 256          // K2: rows per range
#define NSLICE 16        // K2: j-slices per range

// ---------------------------------------------------------------------------
// Kernel 1 (prep + quad-split prefix decide).  [R6-validated, absmax=0.0]
// 4 threads per row; each scans 64 of the 256 prefix columns
// ([0,PRE_PB) u [N,N+PRE_PB)), combined via shfl_xor within the quad.
// Grid = M/64 blocks -> all 256 CUs; critical path 64 iterations.
// Prefix tile interleaved in LDS (phys = (k&63)*4 + (k>>6)) -> the quad's 4
// concurrent reads hit 4 consecutive float4s (conflict-free broadcast).
// Survivors ~ M/(2*PRE_PB+1) ~ 127.  Also zeroes accum[0..7] and the
// per-range ticket counters (used only by kernel 2 -> no race).
// ---------------------------------------------------------------------------
__global__ void __launch_bounds__(TPB) prep_prefix(
        const float* __restrict__ kp_before,
        const float* __restrict__ pred,
        const float* __restrict__ pose,
        float4* __restrict__ gt4,
        float* __restrict__ thr,
        unsigned int* __restrict__ good,
        float* __restrict__ accum,
        unsigned int* __restrict__ rctr,
        int M, int N, int nranges) {
    __shared__ float4 shg[2 * PRE_PB];   // interleaved: (k&63)*4 + (k>>6)
    int tid = threadIdx.x;
    if (blockIdx.x == 0) {
        if (tid < 8) accum[tid] = 0.0f;              // sums + ticket @ [7]
        for (int k = tid; k < nranges; k += TPB) rctr[k] = 0u;
    }

    int row = blockIdx.x * ROWS_PB + (tid >> 2);
    int sub = tid & 3;
    bool rowvalid = (row < M);
    int i = rowvalid ? row : (M - 1);

    // --- row setup (each quad thread redundantly, bit-identical) ---
    float sp, tp0, tp1, tp2, dii;
    float g0, g1, g2, sg;
    {
        int b = i / N;
        const float* P = pose + b * 12;
        float k0 = kp_before[3*i+0];
        float k1 = kp_before[3*i+1];
        float k2 = kp_before[3*i+2];
        g0 = fmaf(P[2],  k2, fmaf(P[1], k1, P[0]*k0)) + P[3];
        g1 = fmaf(P[6],  k2, fmaf(P[5], k1, P[4]*k0)) + P[7];
        g2 = fmaf(P[10], k2, fmaf(P[9], k1, P[8]*k0)) + P[11];
        {
            #pragma clang fp contract(off)
            sg = (g0*g0 + g1*g1) + g2*g2;   // numpy sum order, no FMA
        }
        float p0 = pred[3*i+0], p1 = pred[3*i+1], p2 = pred[3*i+2];
        {
            #pragma clang fp contract(off)
            sp = (p0*p0 + p1*p1) + p2*p2;
        }
        tp0 = 2.0f*p0; tp1 = 2.0f*p1; tp2 = 2.0f*p2;
        float dot2 = fmaf(tp2, g2, fmaf(tp1, g1, tp0*g0));
        float v = (sp + sg) - dot2;
        dii = fmaxf(v, 0.0f);
    }
    if (sub == 0 && rowvalid) {
        gt4[i] = make_float4(g0, g1, g2, sg);
        thr[i] = dii;
    }

    // --- prefix tile recompute into LDS (256 threads -> 256 entries) ---
    {
        int k = tid;                               // logical prefix col index
        int jp = (k < PRE_PB) ? k : (N + k - PRE_PB);
        if (jp >= M) jp = k - PRE_PB;              // B==1 fallback: dup tile0
        const float* Pj = pose + (jp / N) * 12;
        float q0 = kp_before[3*jp+0];
        float q1 = kp_before[3*jp+1];
        float q2 = kp_before[3*jp+2];
        float h0 = fmaf(Pj[2],  q2, fmaf(Pj[1], q1, Pj[0]*q0)) + Pj[3];
        float h1 = fmaf(Pj[6],  q2, fmaf(Pj[5], q1, Pj[4]*q0)) + Pj[7];
        float h2 = fmaf(Pj[10], q2, fmaf(Pj[9], q1, Pj[8]*q0)) + Pj[11];
        float hh;
        {
            #pragma clang fp contract(off)
            hh = (h0*h0 + h1*h1) + h2*h2;
        }
        shg[(k & 63) * 4 + (k >> 6)] = make_float4(h0, h1, h2, hh);
    }
    __syncthreads();

    // --- scan: this thread's 64 columns are logical k = sub*64 + it ---
    bool dirty = (i < PRE_PB) || (i >= N && i < N + PRE_PB);
    bool bad;
    if (!dirty) {
        float mn = __uint_as_float(0x7f7fffffu);   // FLT_MAX
        #pragma unroll 8
        for (int it = 0; it < 64; it++) {
            float4 g = shg[it * 4 + sub];
            float v = (sp + g.w) -
                      fmaf(tp2, g.z, fmaf(tp1, g.y, tp0 * g.x));
            mn = fminf(mn, v);
        }
        // quad combine: after xor1, lanes{0,1}=min(tile0)=mnl, {2,3}=mnr
        float v1 = fminf(mn, __shfl_xor(mn, 1, 64));
        float v2 = __shfl_xor(v1, 2, 64);
        if (i >= N + PRE_PB) {
            float mall = fminf(v1, v2);            // both tiles j < i
            bad = (fmaxf(mall, 0.0f) <= dii);
        } else {
            // PRE_PB <= i < N: tile0 all j<i (<=), tile1 all j>i (<)
            bad = (fmaxf(v1, 0.0f) <= dii) || (fmaxf(v2, 0.0f) < dii);
        }
    } else {
        // rows inside a prefix tile: generic predicate with explicit j
        bool h = false;
        #pragma unroll 8
        for (int it = 0; it < 64; it++) {
            int k = sub * 64 + it;
            int j = (k < PRE_PB) ? k : (N + k - PRE_PB);
            if (j >= M) j = k - PRE_PB;            // B==1 fallback (dup tile)
            float4 g = shg[it * 4 + sub];
            float v = (sp + g.w) -
                      fmaf(tp2, g.z, fmaf(tp1, g.y, tp0 * g.x));
            float c = fmaxf(v, 0.0f);
            h = h || (c < dii && j != i) || (c == dii && j < i);
        }
        int hv = h ? 1 : 0;
        hv |= __shfl_xor(hv, 1, 64);
        hv |= __shfl_xor(hv, 2, 64);
        bad = (hv != 0);
    }
    if (sub == 0 && rowvalid) good[i] = bad ? 0u : 1u;
}

// ---------------------------------------------------------------------------
// Kernel 2 (sliced resolve + per-range-ticket finalize + scalar).
// Grid = nranges x NSLICE (64 x 16 = 1024).  Each block gathers its
// 256-row range's prefix survivors (expected ~2) and checks them against its
// ~504-column slice of each non-prefix half: 4 pre-issued loads per thread =
// ONE memory round trip per candidate (R5-validated flat pattern; batch fits
// in 16 VGPRs, unlike R6's 64).  Hits write good[r]=0 (benign race).
// Then fence + per-range ticket: the 16th slice-block of the range finalizes
// its 256 rows (coherent atomic reads of final good[]), wave-reduces
// (summation groups = contiguous 64 rows, identical to all passing rounds),
// atomicAdds into accum, and a global ticket (accum[7], target=nranges)
// computes the final scalar.
// ---------------------------------------------------------------------------
__device__ inline float wave_red(float v) {
    #pragma unroll
    for (int off = 32; off > 0; off >>= 1) v += __shfl_down(v, off, 64);
    return v;
}

__global__ void __launch_bounds__(TPB) resolve_finalize(
        const float* __restrict__ pred,
        const float4* __restrict__ gt4,
        const float* __restrict__ thr,
        unsigned int* __restrict__ good,
        const float* __restrict__ ow,
        const float* __restrict__ logits,
        float* __restrict__ accum,
        unsigned int* __restrict__ rctr,
        float* __restrict__ out,
        int M, int N, int nranges) {
    __shared__ int cands[RNG];
    __shared__ int ncand;
    __shared__ int lastflag;
    int tid = threadIdx.x;
    int rg = blockIdx.x >> 4;        // range index
    int s  = blockIdx.x & (NSLICE - 1);
    int r0 = rg * RNG;

    if (tid == 0) ncand = 0;
    __syncthreads();
    int i = r0 + tid;
    unsigned int gi = (i < M) ? good[i] : 0u;
    if (gi == 1u) { int p = atomicAdd(&ncand, 1); cands[p] = i; }
    __syncthreads();
    int nc = ncand;

    // slice bounds over the two non-prefix column ranges
    int C0 = N - PRE_PB;
    int per0 = (C0 + NSLICE - 1) / NSLICE;
    int js0 = PRE_PB + s * per0;
    int je0 = js0 + per0; if (je0 > N) je0 = N;
    int C1 = (M - N) - PRE_PB; if (C1 < 0) C1 = 0;
    int per1 = (C1 + NSLICE - 1) / NSLICE;
    int js1 = N + PRE_PB + s * per1;
    int je1 = js1 + per1; if (je1 > M) je1 = M;

    for (int e = 0; e < nc; e++) {
        int r = cands[e];
        float p0 = pred[3*r+0], p1 = pred[3*r+1], p2 = pred[3*r+2];
        float sp;
        {
            #pragma clang fp contract(off)
            sp = (p0*p0 + p1*p1) + p2*p2;
        }
        float tp0 = 2.0f*p0, tp1 = 2.0f*p1, tp2 = 2.0f*p2;
        float dii = thr[r];

        // 4 independent loads, all issued before first use (one round trip)
        int ja0 = js0 + tid;        bool va0 = (ja0 < je0);
        int jb0 = ja0 + TPB;        bool vb0 = (jb0 < je0);
        int ja1 = js1 + tid;        bool va1 = (C1 > 0) && (ja1 < je1);
        int jb1 = ja1 + TPB;        bool vb1 = (C1 > 0) && (jb1 < je1);
        float4 gA0 = gt4[va0 ? ja0 : PRE_PB];
        float4 gB0 = gt4[vb0 ? jb0 : PRE_PB];
        float4 gA1 = gt4[va1 ? ja1 : PRE_PB];
        float4 gB1 = gt4[vb1 ? jb1 : PRE_PB];

        bool h = false;
        {
            float v = (sp + gA0.w) -
                      fmaf(tp2, gA0.z, fmaf(tp1, gA0.y, tp0 * gA0.x));
            float c = fmaxf(v, 0.0f);
            h = h || (va0 && ((c < dii && ja0 != r) || (c == dii && ja0 < r)));
        }
        {
            float v = (sp + gB0.w) -
                      fmaf(tp2, gB0.z, fmaf(tp1, gB0.y, tp0 * gB0.x));
            float c = fmaxf(v, 0.0f);
            h = h || (vb0 && ((c < dii && jb0 != r) || (c == dii && jb0 < r)));
        }
        {
            float v = (sp + gA1.w) -
                      fmaf(tp2, gA1.z, fmaf(tp1, gA1.y, tp0 * gA1.x));
            float c = fmaxf(v, 0.0f);
            h = h || (va1 && ((c < dii && ja1 != r) || (c == dii && ja1 < r)));
        }
        {
            float v = (sp + gB1.w) -
                      fmaf(tp2, gB1.z, fmaf(tp1, gB1.y, tp0 * gB1.x));
            float c = fmaxf(v, 0.0f);
            h = h || (vb1 && ((c < dii && jb1 != r) || (c == dii && jb1 < r)));
        }
        if (h) good[r] = 0u;    // benign: only 0 is ever written
    }

    // per-range ticket: the last of the 16 slice-blocks finalizes the range
    __threadfence();            // publish this thread's good[] stores
    __syncthreads();
    if (tid == 0) {
        unsigned int old = atomicAdd(&rctr[rg], 1u);
        lastflag = (old == NSLICE - 1) ? 1 : 0;
    }
    __syncthreads();
    if (!lastflag) return;

    // finalize this range's 256 rows (one per thread); final good[] via
    // coherent atomic reads (same guaranteed path as the validated tail)
    float werr = 0.f, wsum = 0.f, b1 = 0.f, c1 = 0.f, b0 = 0.f, c0 = 0.f;
    if (i < M) {
        unsigned int gfin = atomicOr(&good[i], 0u);
        float x = logits[i];
        float l1p = log1pf(expf(-fabsf(x)));   // softplus tail
        if (gfin == 1u) {                      // label 1: bce = softplus(-x)
            b1 = fmaxf(-x, 0.f) + l1p; c1 = 1.f;
        } else {                               // label 0: bce = softplus(x)
            b0 = fmaxf(x, 0.f) + l1p;  c0 = 1.f;
        }
        float4 g = gt4[i];
        float q0 = pred[3*i+0], q1 = pred[3*i+1], q2 = pred[3*i+2];
        float e2 = (fabsf(q0 - g.x) + fabsf(q1 - g.y)) + fabsf(q2 - g.z);
        float wi = ow[i];
        werr = wi * e2;
        wsum = wi;
    }
    werr = wave_red(werr); wsum = wave_red(wsum);
    b1 = wave_red(b1); c1 = wave_red(c1);
    b0 = wave_red(b0); c0 = wave_red(c0);
    if ((tid & 63) == 0) {
        atomicAdd(&accum[0], werr);
        atomicAdd(&accum[1], wsum);
        atomicAdd(&accum[2], b1);
        atomicAdd(&accum[3], c1);
        atomicAdd(&accum[4], b0);
        atomicAdd(&accum[5], c0);
    }
    __threadfence();          // make this block's atomics device-visible
    __syncthreads();
    if (tid == 0) {
        unsigned int* ctr = (unsigned int*)&accum[7];
        unsigned int old = atomicAdd(ctr, 1u);
        if (old == (unsigned int)(nranges - 1)) {
            // atomic reads: guaranteed-coherent path for others' atomics
            float a0 = atomicAdd(&accum[0], 0.f);
            float a1 = atomicAdd(&accum[1], 0.f);
            float a2 = atomicAdd(&accum[2], 0.f);
            float a3 = atomicAdd(&accum[3], 0.f);
            float a4 = atomicAdd(&accum[4], 0.f);
            float a5 = atomicAdd(&accum[5], 0.f);
            float mean_err = a0 / fmaxf(a1, 1e-6f);
            float g1v = (a3 > 0.f) ? (a2 / fmaxf(a3, 1.f)) : 0.f;
            float g0v = (a5 > 0.f) ? (a4 / fmaxf(a5, 1.f)) : 0.f;
            out[0] = mean_err + (g0v * 0.5f + g1v * 0.5f);
        }
    }
}

extern "C" void kernel_launch(void* const* d_in, const int* in_sizes, int n_in,
                              void* d_out, int out_size, void* d_ws, size_t ws_size,
                              hipStream_t stream) {
    const float* kp_before = (const float*)d_in[0];
    const float* pred      = (const float*)d_in[1];
    const float* pose      = (const float*)d_in[2];
    const float* ow        = (const float*)d_in[3];
    const float* logits    = (const float*)d_in[4];
    float* out = (float*)d_out;

    int M = in_sizes[3];            // B*N = 16384
    int B = in_sizes[2] / 12;       // 2
    int N = M / B;                  // 8192

    char* ws = (char*)d_ws;
    float4* gt4 = (float4*)ws;                                  // M*16 B
    float* thr = (float*)(ws + (size_t)M * 16);                 // M*4 B
    unsigned int* good = (unsigned int*)(ws + (size_t)M * 20);  // M*4 B
    float* accum = (float*)(ws + (size_t)M * 24);               // 32 B ([7]=ticket)
    unsigned int* rctr = (unsigned int*)(ws + (size_t)M * 24 + 32);

    int nranges = (M + RNG - 1) / RNG;                          // 64
    int nblk1 = (M + ROWS_PB - 1) / ROWS_PB;                    // 256

    hipLaunchKernelGGL(prep_prefix, dim3(nblk1), dim3(TPB), 0, stream,
                       kp_before, pred, pose, gt4, thr, good, accum, rctr,
                       M, N, nranges);

    hipLaunchKernelGGL(resolve_finalize, dim3(nranges * NSLICE), dim3(TPB), 0,
                       stream, pred, gt4, thr, good, ow, logits, accum, rctr,
                       out, M, N, nranges);
}

// Round 9
// 100.126 us; speedup vs baseline: 1.5660x; 1.5660x over previous
//
#include <hip/hip_runtime.h>
#include <cstdint>

#define TPB 256
#define PRE_PB 128       // prefix columns taken from EACH batch (2*PRE_PB = 256)
#define ROWS_PB 64       // K1: rows per block (quad-split: 4 threads per row)
#define RNG 256          // K2: rows per range
#define NSLICE 16        // K2: j-slices per range

// ---------------------------------------------------------------------------
// Kernel 1 (prep + quad-split prefix decide).  [R6-validated, absmax=0.0]
// 4 threads per row; each scans 64 of the 256 prefix columns
// ([0,PRE_PB) u [N,N+PRE_PB)), combined via shfl_xor within the quad.
// Grid = M/64 blocks -> all 256 CUs; critical path 64 iterations.
// Prefix tile interleaved in LDS (phys = (k&63)*4 + (k>>6)) -> the quad's 4
// concurrent reads hit 4 consecutive float4s (conflict-free broadcast).
// Survivors ~ M/(2*PRE_PB+1) ~ 127.  Also zeroes accum[0..7].
// All arithmetic bit-matches the validated baseline: dot via ascending-k FMA
// chain, sums via (a+b)+c with contraction off, 2*dot via pre-scaled
// operands (exact), clamp commutes with min.
// ---------------------------------------------------------------------------
__global__ void __launch_bounds__(TPB) prep_prefix(
        const float* __restrict__ kp_before,
        const float* __restrict__ pred,
        const float* __restrict__ pose,
        float4* __restrict__ gt4,
        float* __restrict__ thr,
        unsigned int* __restrict__ good,
        float* __restrict__ accum,
        int M, int N) {
    __shared__ float4 shg[2 * PRE_PB];   // interleaved: (k&63)*4 + (k>>6)
    int tid = threadIdx.x;
    if (blockIdx.x == 0 && tid < 8) accum[tid] = 0.0f;   // sums + ticket @ [7]

    int row = blockIdx.x * ROWS_PB + (tid >> 2);
    int sub = tid & 3;
    bool rowvalid = (row < M);
    int i = rowvalid ? row : (M - 1);

    // --- row setup (each quad thread redundantly, bit-identical) ---
    float sp, tp0, tp1, tp2, dii;
    float g0, g1, g2, sg;
    {
        int b = i / N;
        const float* P = pose + b * 12;
        float k0 = kp_before[3*i+0];
        float k1 = kp_before[3*i+1];
        float k2 = kp_before[3*i+2];
        g0 = fmaf(P[2],  k2, fmaf(P[1], k1, P[0]*k0)) + P[3];
        g1 = fmaf(P[6],  k2, fmaf(P[5], k1, P[4]*k0)) + P[7];
        g2 = fmaf(P[10], k2, fmaf(P[9], k1, P[8]*k0)) + P[11];
        {
            #pragma clang fp contract(off)
            sg = (g0*g0 + g1*g1) + g2*g2;   // numpy sum order, no FMA
        }
        float p0 = pred[3*i+0], p1 = pred[3*i+1], p2 = pred[3*i+2];
        {
            #pragma clang fp contract(off)
            sp = (p0*p0 + p1*p1) + p2*p2;
        }
        tp0 = 2.0f*p0; tp1 = 2.0f*p1; tp2 = 2.0f*p2;
        float dot2 = fmaf(tp2, g2, fmaf(tp1, g1, tp0*g0));
        float v = (sp + sg) - dot2;
        dii = fmaxf(v, 0.0f);
    }
    if (sub == 0 && rowvalid) {
        gt4[i] = make_float4(g0, g1, g2, sg);
        thr[i] = dii;
    }

    // --- prefix tile recompute into LDS (256 threads -> 256 entries) ---
    {
        int k = tid;                               // logical prefix col index
        int jp = (k < PRE_PB) ? k : (N + k - PRE_PB);
        if (jp >= M) jp = k - PRE_PB;              // B==1 fallback: dup tile0
        const float* Pj = pose + (jp / N) * 12;
        float q0 = kp_before[3*jp+0];
        float q1 = kp_before[3*jp+1];
        float q2 = kp_before[3*jp+2];
        float h0 = fmaf(Pj[2],  q2, fmaf(Pj[1], q1, Pj[0]*q0)) + Pj[3];
        float h1 = fmaf(Pj[6],  q2, fmaf(Pj[5], q1, Pj[4]*q0)) + Pj[7];
        float h2 = fmaf(Pj[10], q2, fmaf(Pj[9], q1, Pj[8]*q0)) + Pj[11];
        float hh;
        {
            #pragma clang fp contract(off)
            hh = (h0*h0 + h1*h1) + h2*h2;
        }
        shg[(k & 63) * 4 + (k >> 6)] = make_float4(h0, h1, h2, hh);
    }
    __syncthreads();

    // --- scan: this thread's 64 columns are logical k = sub*64 + it ---
    bool dirty = (i < PRE_PB) || (i >= N && i < N + PRE_PB);
    bool bad;
    if (!dirty) {
        float mn = __uint_as_float(0x7f7fffffu);   // FLT_MAX
        #pragma unroll 8
        for (int it = 0; it < 64; it++) {
            float4 g = shg[it * 4 + sub];
            float v = (sp + g.w) -
                      fmaf(tp2, g.z, fmaf(tp1, g.y, tp0 * g.x));
            mn = fminf(mn, v);
        }
        // quad combine: after xor1, lanes{0,1}=min(tile0)=mnl, {2,3}=mnr
        float v1 = fminf(mn, __shfl_xor(mn, 1, 64));
        float v2 = __shfl_xor(v1, 2, 64);
        if (i >= N + PRE_PB) {
            float mall = fminf(v1, v2);            // both tiles j < i
            bad = (fmaxf(mall, 0.0f) <= dii);
        } else {
            // PRE_PB <= i < N: tile0 all j<i (<=), tile1 all j>i (<)
            bad = (fmaxf(v1, 0.0f) <= dii) || (fmaxf(v2, 0.0f) < dii);
        }
    } else {
        // rows inside a prefix tile: generic predicate with explicit j
        bool h = false;
        #pragma unroll 8
        for (int it = 0; it < 64; it++) {
            int k = sub * 64 + it;
            int j = (k < PRE_PB) ? k : (N + k - PRE_PB);
            if (j >= M) j = k - PRE_PB;            // B==1 fallback (dup tile)
            float4 g = shg[it * 4 + sub];
            float v = (sp + g.w) -
                      fmaf(tp2, g.z, fmaf(tp1, g.y, tp0 * g.x));
            float c = fmaxf(v, 0.0f);
            h = h || (c < dii && j != i) || (c == dii && j < i);
        }
        int hv = h ? 1 : 0;
        hv |= __shfl_xor(hv, 1, 64);
        hv |= __shfl_xor(hv, 2, 64);
        bad = (hv != 0);
    }
    if (sub == 0 && rowvalid) good[i] = bad ? 0u : 1u;
}

// ---------------------------------------------------------------------------
// Kernel 2 (sliced resolve, FENCE-FREE).  [R5-validated structure]
// Grid = nranges x NSLICE (64 x 16 = 1024).  Each block gathers its 256-row
// range's prefix survivors (expected ~2) and checks them against its
// ~504-column slice of each non-prefix half: 4 pre-issued loads per thread =
// ONE memory round trip per candidate.  Hits write good[r]=0 (benign race;
// only 0 is ever written).  NO __threadfence, NO ticket: R8 showed 2048
// per-block device fences (L2 wb/inv on non-coherent-XCD gfx950) cost ~55us;
// the kernel boundary provides the same ordering once, for free.
// ---------------------------------------------------------------------------
__global__ void __launch_bounds__(TPB) resolve_kernel(
        const float* __restrict__ pred,
        const float4* __restrict__ gt4,
        const float* __restrict__ thr,
        unsigned int* __restrict__ good,
        int M, int N) {
    __shared__ int cands[RNG];
    __shared__ int ncand;
    int tid = threadIdx.x;
    int s  = blockIdx.x & (NSLICE - 1);
    int r0 = (blockIdx.x >> 4) * RNG;
    if (tid == 0) ncand = 0;
    __syncthreads();
    int i = r0 + tid;
    if (i < M && good[i] == 1u) { int p = atomicAdd(&ncand, 1); cands[p] = i; }
    __syncthreads();
    int nc = ncand;
    if (nc == 0) return;

    // slice bounds over the two non-prefix column ranges
    int C0 = N - PRE_PB;
    int per0 = (C0 + NSLICE - 1) / NSLICE;
    int js0 = PRE_PB + s * per0;
    int je0 = js0 + per0; if (je0 > N) je0 = N;
    int C1 = (M - N) - PRE_PB; if (C1 < 0) C1 = 0;
    int per1 = (C1 + NSLICE - 1) / NSLICE;
    int js1 = N + PRE_PB + s * per1;
    int je1 = js1 + per1; if (je1 > M) je1 = M;

    for (int e = 0; e < nc; e++) {
        int r = cands[e];
        float p0 = pred[3*r+0], p1 = pred[3*r+1], p2 = pred[3*r+2];
        float sp;
        {
            #pragma clang fp contract(off)
            sp = (p0*p0 + p1*p1) + p2*p2;
        }
        float tp0 = 2.0f*p0, tp1 = 2.0f*p1, tp2 = 2.0f*p2;
        float dii = thr[r];

        // 4 independent loads, all issued before first use (one round trip)
        int ja0 = js0 + tid;        bool va0 = (ja0 < je0);
        int jb0 = ja0 + TPB;        bool vb0 = (jb0 < je0);
        int ja1 = js1 + tid;        bool va1 = (C1 > 0) && (ja1 < je1);
        int jb1 = ja1 + TPB;        bool vb1 = (C1 > 0) && (jb1 < je1);
        float4 gA0 = gt4[va0 ? ja0 : PRE_PB];
        float4 gB0 = gt4[vb0 ? jb0 : PRE_PB];
        float4 gA1 = gt4[va1 ? ja1 : PRE_PB];
        float4 gB1 = gt4[vb1 ? jb1 : PRE_PB];

        bool h = false;
        {
            float v = (sp + gA0.w) -
                      fmaf(tp2, gA0.z, fmaf(tp1, gA0.y, tp0 * gA0.x));
            float c = fmaxf(v, 0.0f);
            h = h || (va0 && ((c < dii && ja0 != r) || (c == dii && ja0 < r)));
        }
        {
            float v = (sp + gB0.w) -
                      fmaf(tp2, gB0.z, fmaf(tp1, gB0.y, tp0 * gB0.x));
            float c = fmaxf(v, 0.0f);
            h = h || (vb0 && ((c < dii && jb0 != r) || (c == dii && jb0 < r)));
        }
        {
            float v = (sp + gA1.w) -
                      fmaf(tp2, gA1.z, fmaf(tp1, gA1.y, tp0 * gA1.x));
            float c = fmaxf(v, 0.0f);
            h = h || (va1 && ((c < dii && ja1 != r) || (c == dii && ja1 < r)));
        }
        {
            float v = (sp + gB1.w) -
                      fmaf(tp2, gB1.z, fmaf(tp1, gB1.y, tp0 * gB1.x));
            float c = fmaxf(v, 0.0f);
            h = h || (vb1 && ((c < dii && jb1 != r) || (c == dii && jb1 < r)));
        }
        if (h) good[r] = 0u;    // benign: only 0 is ever written
    }
}

// ---------------------------------------------------------------------------
// Kernel 3: per-point BCE (balanced groups) + weighted L1; wave reduce,
// atomicAdd into accum[0..5]; last-block ticket (accum[7]) computes the
// final scalar.  [R5-validated verbatim: 64 blocks -> only 128 fences]
// ---------------------------------------------------------------------------
__device__ inline float wave_red(float v) {
    #pragma unroll
    for (int off = 32; off > 0; off >>= 1) v += __shfl_down(v, off, 64);
    return v;
}

__global__ void __launch_bounds__(TPB) finalize_kernel(
        const float* __restrict__ pred,
        const float4* __restrict__ gt4,
        const float* __restrict__ ow,
        const float* __restrict__ logits,
        const unsigned int* __restrict__ good,
        float* __restrict__ accum,
        float* __restrict__ out,
        int M) {
    float werr = 0.f, wsum = 0.f, b1 = 0.f, c1 = 0.f, b0 = 0.f, c0 = 0.f;
    int stride = gridDim.x * blockDim.x;
    for (int i = blockIdx.x * blockDim.x + threadIdx.x; i < M; i += stride) {
        float x = logits[i];
        float l1p = log1pf(expf(-fabsf(x)));   // softplus tail
        if (good[i] == 1u) {                   // label 1: bce = softplus(-x)
            b1 += fmaxf(-x, 0.f) + l1p; c1 += 1.f;
        } else {                               // label 0: bce = softplus(x)
            b0 += fmaxf(x, 0.f) + l1p;  c0 += 1.f;
        }
        float4 g = gt4[i];
        float p0 = pred[3*i+0], p1 = pred[3*i+1], p2 = pred[3*i+2];
        float e = (fabsf(p0 - g.x) + fabsf(p1 - g.y)) + fabsf(p2 - g.z);
        float wi = ow[i];
        werr += wi * e;
        wsum += wi;
    }
    werr = wave_red(werr); wsum = wave_red(wsum);
    b1 = wave_red(b1); c1 = wave_red(c1);
    b0 = wave_red(b0); c0 = wave_red(c0);
    if ((threadIdx.x & 63) == 0) {
        atomicAdd(&accum[0], werr);
        atomicAdd(&accum[1], wsum);
        atomicAdd(&accum[2], b1);
        atomicAdd(&accum[3], c1);
        atomicAdd(&accum[4], b0);
        atomicAdd(&accum[5], c0);
    }
    __threadfence();          // make this block's atomics device-visible
    __syncthreads();
    if (threadIdx.x == 0) {
        unsigned int* ctr = (unsigned int*)&accum[7];
        unsigned int old = atomicAdd(ctr, 1u);
        if (old == gridDim.x - 1) {
            // atomic reads: guaranteed-coherent path for others' atomics
            float a0 = atomicAdd(&accum[0], 0.f);
            float a1 = atomicAdd(&accum[1], 0.f);
            float a2 = atomicAdd(&accum[2], 0.f);
            float a3 = atomicAdd(&accum[3], 0.f);
            float a4 = atomicAdd(&accum[4], 0.f);
            float a5 = atomicAdd(&accum[5], 0.f);
            float mean_err = a0 / fmaxf(a1, 1e-6f);
            float g1v = (a3 > 0.f) ? (a2 / fmaxf(a3, 1.f)) : 0.f;
            float g0v = (a5 > 0.f) ? (a4 / fmaxf(a5, 1.f)) : 0.f;
            out[0] = mean_err + (g0v * 0.5f + g1v * 0.5f);
        }
    }
}

extern "C" void kernel_launch(void* const* d_in, const int* in_sizes, int n_in,
                              void* d_out, int out_size, void* d_ws, size_t ws_size,
                              hipStream_t stream) {
    const float* kp_before = (const float*)d_in[0];
    const float* pred      = (const float*)d_in[1];
    const float* pose      = (const float*)d_in[2];
    const float* ow        = (const float*)d_in[3];
    const float* logits    = (const float*)d_in[4];
    float* out = (float*)d_out;

    int M = in_sizes[3];            // B*N = 16384
    int B = in_sizes[2] / 12;       // 2
    int N = M / B;                  // 8192

    char* ws = (char*)d_ws;
    float4* gt4 = (float4*)ws;                                  // M*16 B
    float* thr = (float*)(ws + (size_t)M * 16);                 // M*4 B
    unsigned int* good = (unsigned int*)(ws + (size_t)M * 20);  // M*4 B
    float* accum = (float*)(ws + (size_t)M * 24);               // 32 B ([7]=ticket)

    int nranges = (M + RNG - 1) / RNG;                          // 64
    int nblk1 = (M + ROWS_PB - 1) / ROWS_PB;                    // 256

    hipLaunchKernelGGL(prep_prefix, dim3(nblk1), dim3(TPB), 0, stream,
                       kp_before, pred, pose, gt4, thr, good, accum, M, N);

    hipLaunchKernelGGL(resolve_kernel, dim3(nranges * NSLICE), dim3(TPB), 0,
                       stream, pred, gt4, thr, good, M, N);

    hipLaunchKernelGGL(finalize_kernel, dim3(nranges), dim3(TPB), 0, stream,
                       pred, gt4, ow, logits, good, accum, out, M);
}

// Round 10
// 99.638 us; speedup vs baseline: 1.5737x; 1.0049x over previous
//
#include <hip/hip_runtime.h>
#include <cstdint>

#define TPB 256
#define TPB2 512         // K2 block size (8 waves)
#define PRE_PB 128       // prefix columns taken from EACH batch (2*PRE_PB = 256)
#define ROWS_PB 64       // K1: rows per block (quad-split: 4 threads per row)
#define RNG 256          // K2: rows per range (one block per range)
#define RB 8             // K2: pre-issued loads per batch (32 VGPRs in flight)

// ---------------------------------------------------------------------------
// Kernel 1 (prep + quad-split prefix decide).  [R6/R9-validated, absmax=0.0]
// 4 threads per row; each scans 64 of the 256 prefix columns
// ([0,PRE_PB) u [N,N+PRE_PB)), combined via shfl_xor within the quad.
// Grid = M/64 blocks -> all 256 CUs; critical path 64 iterations.
// Prefix tile interleaved in LDS (phys = (k&63)*4 + (k>>6)) -> the quad's 4
// concurrent reads hit 4 consecutive float4s (conflict-free broadcast).
// Survivors ~ M/(2*PRE_PB+1) ~ 127.  Also zeroes accum[0..7].
// ---------------------------------------------------------------------------
__global__ void __launch_bounds__(TPB) prep_prefix(
        const float* __restrict__ kp_before,
        const float* __restrict__ pred,
        const float* __restrict__ pose,
        float4* __restrict__ gt4,
        float* __restrict__ thr,
        unsigned int* __restrict__ good,
        float* __restrict__ accum,
        int M, int N) {
    __shared__ float4 shg[2 * PRE_PB];   // interleaved: (k&63)*4 + (k>>6)
    int tid = threadIdx.x;
    if (blockIdx.x == 0 && tid < 8) accum[tid] = 0.0f;   // sums + ticket @ [7]

    int row = blockIdx.x * ROWS_PB + (tid >> 2);
    int sub = tid & 3;
    bool rowvalid = (row < M);
    int i = rowvalid ? row : (M - 1);

    // --- row setup (each quad thread redundantly, bit-identical) ---
    float sp, tp0, tp1, tp2, dii;
    float g0, g1, g2, sg;
    {
        int b = i / N;
        const float* P = pose + b * 12;
        float k0 = kp_before[3*i+0];
        float k1 = kp_before[3*i+1];
        float k2 = kp_before[3*i+2];
        g0 = fmaf(P[2],  k2, fmaf(P[1], k1, P[0]*k0)) + P[3];
        g1 = fmaf(P[6],  k2, fmaf(P[5], k1, P[4]*k0)) + P[7];
        g2 = fmaf(P[10], k2, fmaf(P[9], k1, P[8]*k0)) + P[11];
        {
            #pragma clang fp contract(off)
            sg = (g0*g0 + g1*g1) + g2*g2;   // numpy sum order, no FMA
        }
        float p0 = pred[3*i+0], p1 = pred[3*i+1], p2 = pred[3*i+2];
        {
            #pragma clang fp contract(off)
            sp = (p0*p0 + p1*p1) + p2*p2;
        }
        tp0 = 2.0f*p0; tp1 = 2.0f*p1; tp2 = 2.0f*p2;
        float dot2 = fmaf(tp2, g2, fmaf(tp1, g1, tp0*g0));
        float v = (sp + sg) - dot2;
        dii = fmaxf(v, 0.0f);
    }
    if (sub == 0 && rowvalid) {
        gt4[i] = make_float4(g0, g1, g2, sg);
        thr[i] = dii;
    }

    // --- prefix tile recompute into LDS (256 threads -> 256 entries) ---
    {
        int k = tid;                               // logical prefix col index
        int jp = (k < PRE_PB) ? k : (N + k - PRE_PB);
        if (jp >= M) jp = k - PRE_PB;              // B==1 fallback: dup tile0
        const float* Pj = pose + (jp / N) * 12;
        float q0 = kp_before[3*jp+0];
        float q1 = kp_before[3*jp+1];
        float q2 = kp_before[3*jp+2];
        float h0 = fmaf(Pj[2],  q2, fmaf(Pj[1], q1, Pj[0]*q0)) + Pj[3];
        float h1 = fmaf(Pj[6],  q2, fmaf(Pj[5], q1, Pj[4]*q0)) + Pj[7];
        float h2 = fmaf(Pj[10], q2, fmaf(Pj[9], q1, Pj[8]*q0)) + Pj[11];
        float hh;
        {
            #pragma clang fp contract(off)
            hh = (h0*h0 + h1*h1) + h2*h2;
        }
        shg[(k & 63) * 4 + (k >> 6)] = make_float4(h0, h1, h2, hh);
    }
    __syncthreads();

    // --- scan: this thread's 64 columns are logical k = sub*64 + it ---
    bool dirty = (i < PRE_PB) || (i >= N && i < N + PRE_PB);
    bool bad;
    if (!dirty) {
        float mn = __uint_as_float(0x7f7fffffu);   // FLT_MAX
        #pragma unroll 8
        for (int it = 0; it < 64; it++) {
            float4 g = shg[it * 4 + sub];
            float v = (sp + g.w) -
                      fmaf(tp2, g.z, fmaf(tp1, g.y, tp0 * g.x));
            mn = fminf(mn, v);
        }
        // quad combine: after xor1, lanes{0,1}=min(tile0)=mnl, {2,3}=mnr
        float v1 = fminf(mn, __shfl_xor(mn, 1, 64));
        float v2 = __shfl_xor(v1, 2, 64);
        if (i >= N + PRE_PB) {
            float mall = fminf(v1, v2);            // both tiles j < i
            bad = (fmaxf(mall, 0.0f) <= dii);
        } else {
            // PRE_PB <= i < N: tile0 all j<i (<=), tile1 all j>i (<)
            bad = (fmaxf(v1, 0.0f) <= dii) || (fmaxf(v2, 0.0f) < dii);
        }
    } else {
        // rows inside a prefix tile: generic predicate with explicit j
        bool h = false;
        #pragma unroll 8
        for (int it = 0; it < 64; it++) {
            int k = sub * 64 + it;
            int j = (k < PRE_PB) ? k : (N + k - PRE_PB);
            if (j >= M) j = k - PRE_PB;            // B==1 fallback (dup tile)
            float4 g = shg[it * 4 + sub];
            float v = (sp + g.w) -
                      fmaf(tp2, g.z, fmaf(tp1, g.y, tp0 * g.x));
            float c = fmaxf(v, 0.0f);
            h = h || (c < dii && j != i) || (c == dii && j < i);
        }
        int hv = h ? 1 : 0;
        hv |= __shfl_xor(hv, 1, 64);
        hv |= __shfl_xor(hv, 2, 64);
        bad = (hv != 0);
    }
    if (sub == 0 && rowvalid) good[i] = bad ? 0u : 1u;
}

// ---------------------------------------------------------------------------
// Kernel 2 (fused resolve + finalize + scalar, ONE BLOCK PER RANGE).
// 64 blocks x 512 threads.  Each block gathers its 256-row range's prefix
// survivors (expected ~2) and resolves each against ALL non-prefix columns:
// 512 threads x (2 batches of RB=8 pre-issued loads per half) = 4 memory
// round trips per candidate, no serial chain.  (R6's fused version failed
// with 63 loads/thread and a 64-VGPR batch; this uses 15.75 and 32.)
// Verdicts stay in LDS -- no global good[] writeback needed at all.
// Then finalize of the block's own 256 rows (threads 0..255; wave groups =
// contiguous 64 rows, identical to all passing rounds), atomicAdd into
// accum, and the R5-validated 64-block ticket (128 fences -- cheap; R8
// showed 2048 fences cost ~55us) computes the final scalar.
// ---------------------------------------------------------------------------
__device__ inline float wave_red(float v) {
    #pragma unroll
    for (int off = 32; off > 0; off >>= 1) v += __shfl_down(v, off, 64);
    return v;
}

__global__ void __launch_bounds__(TPB2) resolve_finalize(
        const float* __restrict__ pred,
        const float4* __restrict__ gt4,
        const float* __restrict__ thr,
        const unsigned int* __restrict__ good,
        const float* __restrict__ ow,
        const float* __restrict__ logits,
        float* __restrict__ accum,
        float* __restrict__ out,
        int M, int N) {
    __shared__ int cands[RNG];
    __shared__ unsigned char verd[RNG];
    __shared__ int ncand;
    int tid = threadIdx.x;
    int r0 = blockIdx.x * RNG;

    if (tid == 0) ncand = 0;
    __syncthreads();
    if (tid < RNG) {
        int i = r0 + tid;
        unsigned int gi = (i < M) ? good[i] : 0u;
        verd[tid] = (unsigned char)gi;
        if (gi == 1u) { int p = atomicAdd(&ncand, 1); cands[p] = tid; }
    }
    __syncthreads();
    int nc = ncand;

    for (int e = 0; e < nc; e++) {
        int r = r0 + cands[e];
        float p0 = pred[3*r+0], p1 = pred[3*r+1], p2 = pred[3*r+2];
        float sp;
        {
            #pragma clang fp contract(off)
            sp = (p0*p0 + p1*p1) + p2*p2;
        }
        float tp0 = 2.0f*p0, tp1 = 2.0f*p1, tp2 = 2.0f*p2;
        float dii = thr[r];
        bool h = false;
        #pragma unroll
        for (int half = 0; half < 2; half++) {
            int base = (half == 0) ? PRE_PB : (N + PRE_PB);
            int end  = (half == 0) ? N : M;
            if (base >= end) continue;             // B==1: no second half
            for (int j0 = base + tid; j0 < end; j0 += TPB2 * RB) {
                float4 g[RB];
                #pragma unroll
                for (int b = 0; b < RB; b++) {
                    int j = j0 + b * TPB2;
                    g[b] = gt4[(j < end) ? j : base];   // pre-issued batch
                }
                #pragma unroll
                for (int b = 0; b < RB; b++) {
                    int j = j0 + b * TPB2;
                    float v = (sp + g[b].w) -
                              fmaf(tp2, g[b].z, fmaf(tp1, g[b].y, tp0 * g[b].x));
                    float c = fmaxf(v, 0.0f);
                    h = h || ((j < end) &&
                              ((c < dii && j != r) || (c == dii && j < r)));
                }
            }
        }
        if (h) verd[cands[e]] = 0;   // benign LDS race: only 0 is written
    }
    __syncthreads();

    // finalize this range's 256 rows (threads 0..255, waves 0..3; wave
    // groups = contiguous 64 rows -- identical to all passing rounds)
    if (tid < RNG) {
        int i = r0 + tid;
        float werr = 0.f, wsum = 0.f, b1 = 0.f, c1 = 0.f, b0 = 0.f, c0 = 0.f;
        if (i < M) {
            float x = logits[i];
            float l1p = log1pf(expf(-fabsf(x)));   // softplus tail
            if (verd[tid]) {                       // label 1: bce = softplus(-x)
                b1 = fmaxf(-x, 0.f) + l1p; c1 = 1.f;
            } else {                               // label 0: bce = softplus(x)
                b0 = fmaxf(x, 0.f) + l1p;  c0 = 1.f;
            }
            float4 g = gt4[i];
            float q0 = pred[3*i+0], q1 = pred[3*i+1], q2 = pred[3*i+2];
            float e2 = (fabsf(q0 - g.x) + fabsf(q1 - g.y)) + fabsf(q2 - g.z);
            float wi = ow[i];
            werr = wi * e2;
            wsum = wi;
        }
        werr = wave_red(werr); wsum = wave_red(wsum);
        b1 = wave_red(b1); c1 = wave_red(c1);
        b0 = wave_red(b0); c0 = wave_red(c0);
        if ((tid & 63) == 0) {
            atomicAdd(&accum[0], werr);
            atomicAdd(&accum[1], wsum);
            atomicAdd(&accum[2], b1);
            atomicAdd(&accum[3], c1);
            atomicAdd(&accum[4], b0);
            atomicAdd(&accum[5], c0);
        }
    }
    __threadfence();          // make this block's atomics device-visible
    __syncthreads();
    if (tid == 0) {
        unsigned int* ctr = (unsigned int*)&accum[7];
        unsigned int old = atomicAdd(ctr, 1u);
        if (old == gridDim.x - 1) {
            // atomic reads: guaranteed-coherent path for others' atomics
            float a0 = atomicAdd(&accum[0], 0.f);
            float a1 = atomicAdd(&accum[1], 0.f);
            float a2 = atomicAdd(&accum[2], 0.f);
            float a3 = atomicAdd(&accum[3], 0.f);
            float a4 = atomicAdd(&accum[4], 0.f);
            float a5 = atomicAdd(&accum[5], 0.f);
            float mean_err = a0 / fmaxf(a1, 1e-6f);
            float g1v = (a3 > 0.f) ? (a2 / fmaxf(a3, 1.f)) : 0.f;
            float g0v = (a5 > 0.f) ? (a4 / fmaxf(a5, 1.f)) : 0.f;
            out[0] = mean_err + (g0v * 0.5f + g1v * 0.5f);
        }
    }
}

extern "C" void kernel_launch(void* const* d_in, const int* in_sizes, int n_in,
                              void* d_out, int out_size, void* d_ws, size_t ws_size,
                              hipStream_t stream) {
    const float* kp_before = (const float*)d_in[0];
    const float* pred      = (const float*)d_in[1];
    const float* pose      = (const float*)d_in[2];
    const float* ow        = (const float*)d_in[3];
    const float* logits    = (const float*)d_in[4];
    float* out = (float*)d_out;

    int M = in_sizes[3];            // B*N = 16384
    int B = in_sizes[2] / 12;       // 2
    int N = M / B;                  // 8192

    char* ws = (char*)d_ws;
    float4* gt4 = (float4*)ws;                                  // M*16 B
    float* thr = (float*)(ws + (size_t)M * 16);                 // M*4 B
    unsigned int* good = (unsigned int*)(ws + (size_t)M * 20);  // M*4 B
    float* accum = (float*)(ws + (size_t)M * 24);               // 32 B ([7]=ticket)

    int nranges = (M + RNG - 1) / RNG;                          // 64
    int nblk1 = (M + ROWS_PB - 1) / ROWS_PB;                    // 256

    hipLaunchKernelGGL(prep_prefix, dim3(nblk1), dim3(TPB), 0, stream,
                       kp_before, pred, pose, gt4, thr, good, accum, M, N);

    hipLaunchKernelGGL(resolve_finalize, dim3(nranges), dim3(TPB2), 0, stream,
                       pred, gt4, thr, good, ow, logits, accum, out, M, N);
}